// Round 8
// baseline (1536.409 us; speedup 1.0000x reference)
//
#include <hip/hip_runtime.h>

typedef unsigned short u16;
typedef __attribute__((ext_vector_type(8))) short short8;
typedef __attribute__((ext_vector_type(4))) float f32x4;

constexpr int SA     = 168;   // act row stride (bf16): 336 B, 16B-aligned
constexpr int BLK_E  = 128;   // edges per block
constexpr int NTHR   = 128;   // 2 waves, each owns 64 edges (MT=4)
constexpr int MT     = 4;     // M-tiles per wave
constexpr int J_MAX  = 10;    // N tiles (160 padded)
constexpr int KS_MAX = 5;     // K slices of 32 (160 padded)
constexpr int CHUNK  = 512;   // u16 elems per (j) fragment chunk = 1 KB
constexpr int NCHB   = 12;    // chunks per LDS slice buffer (10 real + 2 pad)
constexpr int BUFSZ  = NCHB * CHUNK;             // 6144 elems per buffer
constexpr int SLICE_G = J_MAX * CHUNK;           // 5120 elems per global slice
constexpr int WSLOT  = KS_MAX * SLICE_G;         // 25600 elems per layer

typedef __attribute__((address_space(1))) const unsigned int gu32;
typedef __attribute__((address_space(3))) unsigned int lu32;

__device__ __forceinline__ void gload_lds16(const u16* g, u16* l) {
    // 16B per lane; LDS dest = wave-uniform base + lane*16 (HW scatter)
    __builtin_amdgcn_global_load_lds((gu32*)g, (lu32*)l, 16, 0, 0);
}

__device__ __forceinline__ u16 f2bf(float f) {  // RNE f32->bf16
    union { float f; unsigned u; } c; c.f = f;
    return (u16)((c.u + 0x7fffu + ((c.u >> 16) & 1u)) >> 16);
}

// activation k-storage permutation (hidden layers):
//  logical n = j*16+col stored at k' = col*8+j (j<8) | 128+col*2+(j-8) (j=8,9)
__device__ __forceinline__ int kperm(int kp) {
    if (kp < 128) return (kp & 7) * 16 + (kp >> 3);
    if (kp < 160) { const int m = kp - 128; return (8 + (m & 1)) * 16 + (m >> 1); }
    return 1 << 30;
}

// ---- prep: weights -> slice-major MFMA fragment order ----------------------
__global__ void prep_weights(const float* __restrict__ W0, const float* __restrict__ W1,
                             const float* __restrict__ W2, const float* __restrict__ W3,
                             const float* __restrict__ W4, u16* __restrict__ out)
{
    const int l = blockIdx.y;
    const float* W; int DI, DO; bool perm;
    if      (l == 0) { W = W0; DI = 13;  DO = 150; perm = false; }
    else if (l == 1) { W = W1; DI = 150; DO = 150; perm = true;  }
    else if (l == 2) { W = W2; DI = 150; DO = 150; perm = true;  }
    else if (l == 3) { W = W3; DI = 150; DO = 150; perm = true;  }
    else             { W = W4; DI = 150; DO = 50;  perm = true;  }
    u16* dst = out + (size_t)l * WSLOT;
    for (int idx = blockIdx.x * blockDim.x + threadIdx.x; idx < WSLOT;
         idx += gridDim.x * blockDim.x) {
        const int chunk = idx / CHUNK;            // = ks*J_MAX + j
        const int within = idx - chunk * CHUNK;
        const int lane = within >> 3, e = within & 7;
        const int ks = chunk / J_MAX, j = chunk - ks * J_MAX;
        const int c = lane & 15, q = lane >> 4;
        const int n = j * 16 + c;
        const int kphys = ks * 32 + q * 8 + e;
        const int klog = perm ? kperm(kphys) : kphys;
        const float v = (n < DO && klog < DI) ? W[klog * DO + n] : 0.f;
        dst[idx] = f2bf(v);
    }
}

// ---- async stage one 10-chunk slice into a 12-chunk LDS buffer -------------
// 2 waves x 5 chunks each.
__device__ __forceinline__ void stage_slice(const u16* __restrict__ gslice,
                                            u16* lbuf, int wv, int lane) {
#pragma unroll
    for (int k = 0; k < 5; ++k) {
        const int c = wv * 5 + k;                  // 0..9
        gload_lds16(gslice + c * CHUNK + lane * 8, lbuf + c * CHUNK);
    }
}

// ---- one K-slice of MFMA: A from act LDS, B from staged slice buffer -------
template<int NT>
__device__ __forceinline__ void gemm_slice(const u16* wb, const u16* actw, int koff,
        int lane, int col, f32x4 (&acc)[MT][NT])
{
    short8 Af[MT];
#pragma unroll
    for (int i = 0; i < MT; ++i)
        Af[i] = *(const short8*)&actw[(i * 16 + col) * SA + koff];
#pragma unroll
    for (int j = 0; j < NT; ++j) {
        const short8 Bf = *(const short8*)&wb[j * CHUNK + lane * 8];
#pragma unroll
        for (int i = 0; i < MT; ++i)
            acc[i][j] = __builtin_amdgcn_mfma_f32_16x16x32_bf16(Af[i], Bf, acc[i][j], 0, 0, 0);
    }
}

// ---- epilogue: bias+relu+bf16, k-permuted in-place store (b128 + b32) ------
__device__ __forceinline__ void epilogue(
    u16* actw, const float* __restrict__ bias,
    int col, int quad, f32x4 (&acc)[MT][10])
{
    float bb[10];
#pragma unroll
    for (int j = 0; j < 10; ++j) {
        const int n = j * 16 + col;
        bb[j] = (n < 150) ? bias[n] : 0.f;
    }
#pragma unroll
    for (int i = 0; i < MT; ++i)
#pragma unroll
        for (int r = 0; r < 4; ++r) {
            u16* row = &actw[(i * 16 + quad * 4 + r) * SA];
            short8 pk;
#pragma unroll
            for (int j = 0; j < 8; ++j)
                pk[j] = (short)f2bf(fmaxf(acc[i][j][r] + bb[j], 0.f));
            *(short8*)&row[col * 8] = pk;                          // k' = col*8 + j
            const u16 lo = f2bf(fmaxf(acc[i][8][r] + bb[8], 0.f));
            const u16 hi = f2bf(fmaxf(acc[i][9][r] + bb[9], 0.f));
            *(unsigned*)&row[128 + col * 2] =                      // k' = 128+col*2+(j-8)
                (unsigned)lo | ((unsigned)hi << 16);
        }
}

// ------------------------------- Edge kernel --------------------------------
// 2 waves x 64 edges (MT=4); act slabs wave-private (no act barriers). Weight
// slices double-buffered in LDS via async global_load_lds; one __syncthreads
// per slice AFTER compute drains the next slice's staging (overlap).
__global__ __launch_bounds__(NTHR, 2) void edge_kernel(
    const float* __restrict__ t, const float* __restrict__ x, const float* __restrict__ Ofx,
    const int* __restrict__ src, const int* __restrict__ tgt,
    const u16* __restrict__ Wt,
    const float* __restrict__ B0, const float* __restrict__ B1, const float* __restrict__ B2,
    const float* __restrict__ B3, const float* __restrict__ B4,
    float* __restrict__ Ep, int n_edges, int copy_mask, size_t copy_elems)
{
    __shared__ __align__(16) u16 act[BLK_E * SA];      // 43008 B
    __shared__ __align__(16) u16 wbuf[2 * BUFSZ];      // 24576 B
    __shared__ int tgt_s[BLK_E];                       // 512 B   -> 2 blocks/CU

    const int tid  = threadIdx.x;
    const int lane = tid & 63;
    const int wv   = tid >> 6;
    const int col  = lane & 15;
    const int quad = lane >> 4;

    const int xcd = (int)(__builtin_amdgcn_s_getreg(6164) & 7u) & copy_mask;
    float* __restrict__ Epc = Ep + (size_t)xcd * copy_elems;

    // ---- gather R' (one edge per thread; wave wv owns edges [wv*64,wv*64+64))
    {
        const int e = tid;
        const long long ge = (long long)blockIdx.x * BLK_E + e;
        const bool valid = ge < n_edges;
        const int s = valid ? src[ge] : 0;
        const int g = valid ? tgt[ge] : 0;
        float v[16];
        const float4 xs = valid ? *(const float4*)&x[(size_t)s * 4] : float4{0, 0, 0, 0};
        const float2 os = valid ? *(const float2*)&Ofx[(size_t)s * 2] : float2{0, 0};
        const float4 xg = valid ? *(const float4*)&x[(size_t)g * 4] : float4{0, 0, 0, 0};
        const float2 og = valid ? *(const float2*)&Ofx[(size_t)g * 2] : float2{0, 0};
        v[0] = xs.x; v[1] = xs.y; v[2] = xs.z; v[3] = xs.w; v[4] = os.x; v[5] = os.y;
        v[6] = xg.x; v[7] = xg.y; v[8] = xg.z; v[9] = xg.w; v[10] = og.x; v[11] = og.y;
        v[12] = valid ? t[0] : 0.f; v[13] = v[14] = v[15] = 0.f;
        short8 c0, c1;
#pragma unroll
        for (int k = 0; k < 8; ++k) { c0[k] = (short)f2bf(v[k]); c1[k] = (short)f2bf(v[k + 8]); }
        u16* row = &act[e * SA];
        *(short8*)&row[0]  = c0;
        *(short8*)&row[8]  = c1;
        *(short8*)&row[16] = short8{0, 0, 0, 0, 0, 0, 0, 0};
        *(short8*)&row[24] = short8{0, 0, 0, 0, 0, 0, 0, 0};
        tgt_s[e] = valid ? g : -1;
    }

    u16* actw = act + wv * 64 * SA;     // this wave's private 64 rows
    const float* Bs[4] = {B0, B1, B2, B3};

    // ---- slice pipeline: stage(s+1) -> compute(s) -> barrier (drains s+1) --
    stage_slice(Wt, wbuf, wv, lane);                        // s=0: (L0,ks0)
    __syncthreads();                                        // drain stage(0)

    f32x4 acc[MT][10];
    int pb = 0;

    // L0 (1 slice)
    stage_slice(Wt + 1 * WSLOT, wbuf + BUFSZ, wv, lane);    // s=1: (L1,ks0)
#pragma unroll
    for (int i = 0; i < MT; ++i)
#pragma unroll
        for (int j = 0; j < 10; ++j) acc[i][j] = f32x4{0.f, 0.f, 0.f, 0.f};
    gemm_slice<10>(wbuf + pb * BUFSZ, actw, quad * 8, lane, col, acc);
    epilogue(actw, B0, col, quad, acc);
    __syncthreads(); pb ^= 1;

    // L1..L3 (5 slices each)
    for (int l = 1; l <= 3; ++l) {
#pragma unroll
        for (int i = 0; i < MT; ++i)
#pragma unroll
            for (int j = 0; j < 10; ++j) acc[i][j] = f32x4{0.f, 0.f, 0.f, 0.f};
#pragma unroll
        for (int ks = 0; ks < 5; ++ks) {
            const u16* nxt = (ks < 4) ? (Wt + (size_t)l * WSLOT + (ks + 1) * SLICE_G)
                                      : (Wt + (size_t)(l + 1) * WSLOT);
            stage_slice(nxt, wbuf + (pb ^ 1) * BUFSZ, wv, lane);
            gemm_slice<10>(wbuf + pb * BUFSZ, actw, ks * 32 + quad * 8, lane, col, acc);
            if (ks == 4) epilogue(actw, Bs[l], col, quad, acc);
            __syncthreads(); pb ^= 1;
        }
    }

    // L4 (5 slices, NT=4, linear) then scatter
    f32x4 acc4[MT][4];
#pragma unroll
    for (int i = 0; i < MT; ++i)
#pragma unroll
        for (int j = 0; j < 4; ++j) acc4[i][j] = f32x4{0.f, 0.f, 0.f, 0.f};
#pragma unroll
    for (int ks = 0; ks < 5; ++ks) {
        if (ks < 4) stage_slice(Wt + 4 * (size_t)WSLOT + (ks + 1) * SLICE_G,
                                wbuf + (pb ^ 1) * BUFSZ, wv, lane);
        gemm_slice<4>(wbuf + pb * BUFSZ, actw, ks * 32 + quad * 8, lane, col, acc4);
        __syncthreads(); pb ^= 1;
    }

    // ---- scatter-add E into XCD-local Ep copy: 4 nodes x 64 B per instr ----
#pragma unroll
    for (int j = 0; j < 4; ++j) {
        const int n = j * 16 + col;
        if (n < 50) {
            const float bb = B4[n];
#pragma unroll
            for (int i = 0; i < MT; ++i)
#pragma unroll
                for (int r = 0; r < 4; ++r) {
                    const int g = tgt_s[wv * 64 + i * 16 + quad * 4 + r];
                    if (g >= 0) atomicAdd(&Epc[(size_t)g * 50 + n], acc4[i][j][r] + bb);
                }
        }
    }
}

// ---------------- Node kernel: reduce copies + fO MLP (fp32 VALU) -----------
template<int DI, int DO, bool RELU>
__device__ __forceinline__ void mlp_layer_t(
    const float* __restrict__ W, const float* __restrict__ B,
    float (*in)[64], float (*out)[64], int tid)
{
    const int et = tid & 15;
    const int jt = tid >> 4;
    constexpr int NG = (DO + 15) / 16;

    float acc0[NG], acc1[NG], acc2[NG], acc3[NG];
#pragma unroll
    for (int g = 0; g < NG; ++g) {
        const int j = jt + 16 * g;
        const float bb = (j < DO) ? B[j] : 0.f;
        acc0[g] = bb; acc1[g] = bb; acc2[g] = bb; acc3[g] = bb;
    }
    for (int k = 0; k < DI; ++k) {
        const float4 a = *(const float4*)&in[k][et * 4];
#pragma unroll
        for (int g = 0; g < NG; ++g) {
            const int j = jt + 16 * g;
            const float wv = (j < DO) ? W[k * DO + j] : 0.f;
            acc0[g] = fmaf(a.x, wv, acc0[g]);
            acc1[g] = fmaf(a.y, wv, acc1[g]);
            acc2[g] = fmaf(a.z, wv, acc2[g]);
            acc3[g] = fmaf(a.w, wv, acc3[g]);
        }
    }
#pragma unroll
    for (int g = 0; g < NG; ++g) {
        const int j = jt + 16 * g;
        if (j < DO) {
            float4 v; v.x = acc0[g]; v.y = acc1[g]; v.z = acc2[g]; v.w = acc3[g];
            if (RELU) {
                v.x = fmaxf(v.x, 0.f); v.y = fmaxf(v.y, 0.f);
                v.z = fmaxf(v.z, 0.f); v.w = fmaxf(v.w, 0.f);
            }
            *(float4*)&out[j][et * 4] = v;
        }
    }
}

__global__ __launch_bounds__(256, 2) void node_kernel(
    const float* __restrict__ Ep, int ncopies, size_t copy_elems,
    const float* __restrict__ W0, const float* __restrict__ B0,
    const float* __restrict__ W1, const float* __restrict__ B1,
    float* __restrict__ P, int n_nodes)
{
    __shared__ float bufA[104][64];
    __shared__ float bufB[104][64];
    const int tid = threadIdx.x;
    const int n0  = blockIdx.x * 64;

    for (int idx = tid; idx < 64 * 50; idx += 256) {
        const int e = idx / 50;
        const int k = idx - e * 50;
        const int n = n0 + e;
        float s = 0.f;
        if (n < n_nodes) {
            const float* p = &Ep[(size_t)n * 50 + k];
            for (int c = 0; c < ncopies; ++c) s += p[(size_t)c * copy_elems];
        }
        bufA[k][e] = s;
    }
    __syncthreads();
    mlp_layer_t<50, 100, true >(W0, B0, bufA, bufB, tid); __syncthreads();
    mlp_layer_t<100, 4, false>(W1, B1, bufB, bufA, tid); __syncthreads();
    for (int idx = tid; idx < 64 * 4; idx += 256) {
        const int e = idx & 63;
        const int j = idx >> 6;
        const int n = n0 + e;
        if (n < n_nodes) P[(size_t)n * 4 + j] = bufA[j][e];
    }
}

// ------------------------------- launcher -----------------------------------
extern "C" void kernel_launch(void* const* d_in, const int* in_sizes, int n_in,
                              void* d_out, int out_size, void* d_ws, size_t ws_size,
                              hipStream_t stream)
{
    const float* t   = (const float*)d_in[0];
    const float* x   = (const float*)d_in[1];
    const float* Ofx = (const float*)d_in[2];
    const int*   src = (const int*)d_in[3];
    const int*   tgt = (const int*)d_in[4];
    const float* W0  = (const float*)d_in[5];  const float* B0 = (const float*)d_in[6];
    const float* W1  = (const float*)d_in[7];  const float* B1 = (const float*)d_in[8];
    const float* W2  = (const float*)d_in[9];  const float* B2 = (const float*)d_in[10];
    const float* W3  = (const float*)d_in[11]; const float* B3 = (const float*)d_in[12];
    const float* W4  = (const float*)d_in[13]; const float* B4 = (const float*)d_in[14];
    const float* OW0 = (const float*)d_in[15]; const float* OB0 = (const float*)d_in[16];
    const float* OW1 = (const float*)d_in[17]; const float* OB1 = (const float*)d_in[18];

    const int n_nodes = in_sizes[1] / 4;
    const int n_edges = in_sizes[3];

    u16*   Wt = (u16*)d_ws;                                // 5*51200 = 256000 B
    float* Ep = (float*)((char*)d_ws + 262144);            // ncopies x [N,50] fp32

    const size_t copy_elems = (size_t)n_nodes * 50;
    const size_t avail = (ws_size > 262144) ? ws_size - 262144 : 0;
    int ncopies = 1;                                        // power of two, <= 4
    while (ncopies * 2 <= 4 &&
           (size_t)(ncopies * 2) * copy_elems * sizeof(float) <= avail)
        ncopies *= 2;
    const int copy_mask = ncopies - 1;

    prep_weights<<<dim3(32, 5), 256, 0, stream>>>(W0, W1, W2, W3, W4, Wt);
    hipMemsetAsync(Ep, 0, (size_t)ncopies * copy_elems * sizeof(float), stream);

    edge_kernel<<<(n_edges + BLK_E - 1) / BLK_E, NTHR, 0, stream>>>(
        t, x, Ofx, src, tgt, Wt, B0, B1, B2, B3, B4,
        Ep, n_edges, copy_mask, copy_elems);

    node_kernel<<<(n_nodes + 63) / 64, 256, 0, stream>>>(
        Ep, ncopies, copy_elems, OW0, OB0, OW1, OB1, (float*)d_out, n_nodes);
}

// Round 9
// 1273.659 us; speedup vs baseline: 1.2063x; 1.2063x over previous
//
#include <hip/hip_runtime.h>

typedef unsigned short u16;
typedef __attribute__((ext_vector_type(8))) short short8;
typedef __attribute__((ext_vector_type(4))) float f32x4;

constexpr int SA     = 168;   // act row stride (bf16): 336 B, 16B-aligned, 2-way banks
constexpr int BLK_E  = 96;    // edges per block
constexpr int NTHR   = 128;   // 2 waves, each owns 48 edges (MT=3)
constexpr int MT     = 3;     // M-tiles per wave
constexpr int J_MAX  = 10;    // N tiles (160 padded)
constexpr int KS_MAX = 5;     // K slices of 32 (160 padded)
constexpr int CHUNK  = 512;   // u16 elems per (j) fragment chunk = 1 KB
constexpr int NCHB   = 10;    // chunks per LDS slice buffer (exact)
constexpr int BUFSZ  = NCHB * CHUNK;             // 5120 elems per buffer
constexpr int SLICE_G = J_MAX * CHUNK;           // 5120 elems per global slice
constexpr int WSLOT  = KS_MAX * SLICE_G;         // 25600 elems per layer

typedef __attribute__((address_space(1))) const unsigned int gu32;
typedef __attribute__((address_space(3))) unsigned int lu32;

__device__ __forceinline__ void gload_lds16(const u16* g, u16* l) {
    // 16B per lane; LDS dest = wave-uniform base + lane*16 (HW scatter)
    __builtin_amdgcn_global_load_lds((gu32*)g, (lu32*)l, 16, 0, 0);
}

__device__ __forceinline__ u16 f2bf(float f) {  // RNE f32->bf16
    union { float f; unsigned u; } c; c.f = f;
    return (u16)((c.u + 0x7fffu + ((c.u >> 16) & 1u)) >> 16);
}

// activation k-storage permutation (hidden layers):
//  logical n = j*16+col stored at k' = col*8+j (j<8) | 128+col*2+(j-8) (j=8,9)
__device__ __forceinline__ int kperm(int kp) {
    if (kp < 128) return (kp & 7) * 16 + (kp >> 3);
    if (kp < 160) { const int m = kp - 128; return (8 + (m & 1)) * 16 + (m >> 1); }
    return 1 << 30;
}

// ---- prep: weights -> slice-major MFMA fragment order ----------------------
__global__ void prep_weights(const float* __restrict__ W0, const float* __restrict__ W1,
                             const float* __restrict__ W2, const float* __restrict__ W3,
                             const float* __restrict__ W4, u16* __restrict__ out)
{
    const int l = blockIdx.y;
    const float* W; int DI, DO; bool perm;
    if      (l == 0) { W = W0; DI = 13;  DO = 150; perm = false; }
    else if (l == 1) { W = W1; DI = 150; DO = 150; perm = true;  }
    else if (l == 2) { W = W2; DI = 150; DO = 150; perm = true;  }
    else if (l == 3) { W = W3; DI = 150; DO = 150; perm = true;  }
    else             { W = W4; DI = 150; DO = 50;  perm = true;  }
    u16* dst = out + (size_t)l * WSLOT;
    for (int idx = blockIdx.x * blockDim.x + threadIdx.x; idx < WSLOT;
         idx += gridDim.x * blockDim.x) {
        const int chunk = idx / CHUNK;            // = ks*J_MAX + j
        const int within = idx - chunk * CHUNK;
        const int lane = within >> 3, e = within & 7;
        const int ks = chunk / J_MAX, j = chunk - ks * J_MAX;
        const int c = lane & 15, q = lane >> 4;
        const int n = j * 16 + c;
        const int kphys = ks * 32 + q * 8 + e;
        const int klog = perm ? kperm(kphys) : kphys;
        const float v = (n < DO && klog < DI) ? W[klog * DO + n] : 0.f;
        dst[idx] = f2bf(v);
    }
}

// ---- async stage one 10-chunk slice: 2 waves x 5 chunks --------------------
__device__ __forceinline__ void stage_slice(const u16* __restrict__ gslice,
                                            u16* lbuf, int wv, int lane) {
#pragma unroll
    for (int k = 0; k < 5; ++k) {
        const int c = wv * 5 + k;                  // 0..9
        gload_lds16(gslice + c * CHUNK + lane * 8, lbuf + c * CHUNK);
    }
}

// ---- one K-slice of MFMA: A from act LDS, B from staged slice buffer -------
template<int NT>
__device__ __forceinline__ void gemm_slice(const u16* wb, const u16* actw, int koff,
        int lane, int col, f32x4 (&acc)[MT][NT])
{
    short8 Af[MT];
#pragma unroll
    for (int i = 0; i < MT; ++i)
        Af[i] = *(const short8*)&actw[(i * 16 + col) * SA + koff];
#pragma unroll
    for (int j = 0; j < NT; ++j) {
        const short8 Bf = *(const short8*)&wb[j * CHUNK + lane * 8];
#pragma unroll
        for (int i = 0; i < MT; ++i)
            acc[i][j] = __builtin_amdgcn_mfma_f32_16x16x32_bf16(Af[i], Bf, acc[i][j], 0, 0, 0);
    }
}

// ---- epilogue: bias+relu+bf16, k-permuted in-place store (b128 + b32) ------
__device__ __forceinline__ void epilogue(
    u16* actw, const float* __restrict__ bias,
    int col, int quad, f32x4 (&acc)[MT][10])
{
    float bb[10];
#pragma unroll
    for (int j = 0; j < 10; ++j) {
        const int n = j * 16 + col;
        bb[j] = (n < 150) ? bias[n] : 0.f;
    }
#pragma unroll
    for (int i = 0; i < MT; ++i)
#pragma unroll
        for (int r = 0; r < 4; ++r) {
            u16* row = &actw[(i * 16 + quad * 4 + r) * SA];
            short8 pk;
#pragma unroll
            for (int j = 0; j < 8; ++j)
                pk[j] = (short)f2bf(fmaxf(acc[i][j][r] + bb[j], 0.f));
            *(short8*)&row[col * 8] = pk;                          // k' = col*8 + j
            const u16 lo = f2bf(fmaxf(acc[i][8][r] + bb[8], 0.f));
            const u16 hi = f2bf(fmaxf(acc[i][9][r] + bb[9], 0.f));
            *(unsigned*)&row[128 + col * 2] =                      // k' = 128+col*2+(j-8)
                (unsigned)lo | ((unsigned)hi << 16);
        }
}

// ------------------------------- Edge kernel --------------------------------
// 2 waves x 48 edges (MT=3); act slabs wave-private (no act barriers). Weight
// slices double-buffered in LDS via async global_load_lds; one __syncthreads
// per slice AFTER compute drains the next slice's staging (overlap).
// LDS = 53.1 KB -> 3 blocks/CU = 6 waves in 3 independent barrier groups.
__global__ __launch_bounds__(NTHR, 2) void edge_kernel(
    const float* __restrict__ t, const float* __restrict__ x, const float* __restrict__ Ofx,
    const int* __restrict__ src, const int* __restrict__ tgt,
    const u16* __restrict__ Wt,
    const float* __restrict__ B0, const float* __restrict__ B1, const float* __restrict__ B2,
    const float* __restrict__ B3, const float* __restrict__ B4,
    float* __restrict__ Ep, int n_edges, int copy_mask, size_t copy_elems)
{
    __shared__ __align__(16) u16 act[BLK_E * SA];      // 32256 B
    __shared__ __align__(16) u16 wbuf[2 * BUFSZ];      // 20480 B
    __shared__ int tgt_s[BLK_E];                       // 384 B  -> 53.1 KB

    const int tid  = threadIdx.x;
    const int lane = tid & 63;
    const int wv   = tid >> 6;
    const int col  = lane & 15;
    const int quad = lane >> 4;

    const int xcd = (int)(__builtin_amdgcn_s_getreg(6164) & 7u) & copy_mask;
    float* __restrict__ Epc = Ep + (size_t)xcd * copy_elems;

    // ---- gather R' (wave-private: wave wv owns edges [wv*48, wv*48+48)) ----
    if (lane < 48) {
        const int e = wv * 48 + lane;
        const long long ge = (long long)blockIdx.x * BLK_E + e;
        const bool valid = ge < n_edges;
        const int s = valid ? src[ge] : 0;
        const int g = valid ? tgt[ge] : 0;
        float v[16];
        const float4 xs = valid ? *(const float4*)&x[(size_t)s * 4] : float4{0, 0, 0, 0};
        const float2 os = valid ? *(const float2*)&Ofx[(size_t)s * 2] : float2{0, 0};
        const float4 xg = valid ? *(const float4*)&x[(size_t)g * 4] : float4{0, 0, 0, 0};
        const float2 og = valid ? *(const float2*)&Ofx[(size_t)g * 2] : float2{0, 0};
        v[0] = xs.x; v[1] = xs.y; v[2] = xs.z; v[3] = xs.w; v[4] = os.x; v[5] = os.y;
        v[6] = xg.x; v[7] = xg.y; v[8] = xg.z; v[9] = xg.w; v[10] = og.x; v[11] = og.y;
        v[12] = valid ? t[0] : 0.f; v[13] = v[14] = v[15] = 0.f;
        short8 c0, c1;
#pragma unroll
        for (int k = 0; k < 8; ++k) { c0[k] = (short)f2bf(v[k]); c1[k] = (short)f2bf(v[k + 8]); }
        u16* row = &act[e * SA];
        *(short8*)&row[0]  = c0;
        *(short8*)&row[8]  = c1;
        *(short8*)&row[16] = short8{0, 0, 0, 0, 0, 0, 0, 0};
        *(short8*)&row[24] = short8{0, 0, 0, 0, 0, 0, 0, 0};
        tgt_s[e] = valid ? g : -1;
    }

    u16* actw = act + wv * 48 * SA;     // this wave's private 48 rows
    const float* Bs[4] = {B0, B1, B2, B3};

    // ---- slice pipeline: stage(s+1) -> compute(s) -> barrier (drains s+1) --
    stage_slice(Wt, wbuf, wv, lane);                        // s=0: (L0,ks0)
    __syncthreads();                                        // drain stage(0)

    f32x4 acc[MT][10];
    int pb = 0;

    // L0 (1 slice)
    stage_slice(Wt + 1 * WSLOT, wbuf + BUFSZ, wv, lane);    // s=1: (L1,ks0)
#pragma unroll
    for (int i = 0; i < MT; ++i)
#pragma unroll
        for (int j = 0; j < 10; ++j) acc[i][j] = f32x4{0.f, 0.f, 0.f, 0.f};
    gemm_slice<10>(wbuf + pb * BUFSZ, actw, quad * 8, lane, col, acc);
    epilogue(actw, B0, col, quad, acc);
    __syncthreads(); pb ^= 1;

    // L1..L3 (5 slices each)
    for (int l = 1; l <= 3; ++l) {
#pragma unroll
        for (int i = 0; i < MT; ++i)
#pragma unroll
            for (int j = 0; j < 10; ++j) acc[i][j] = f32x4{0.f, 0.f, 0.f, 0.f};
#pragma unroll
        for (int ks = 0; ks < 5; ++ks) {
            const u16* nxt = (ks < 4) ? (Wt + (size_t)l * WSLOT + (ks + 1) * SLICE_G)
                                      : (Wt + (size_t)(l + 1) * WSLOT);
            stage_slice(nxt, wbuf + (pb ^ 1) * BUFSZ, wv, lane);
            gemm_slice<10>(wbuf + pb * BUFSZ, actw, ks * 32 + quad * 8, lane, col, acc);
            if (ks == 4) epilogue(actw, Bs[l], col, quad, acc);
            __syncthreads(); pb ^= 1;
        }
    }

    // L4 (5 slices, NT=4, linear) then scatter
    f32x4 acc4[MT][4];
#pragma unroll
    for (int i = 0; i < MT; ++i)
#pragma unroll
        for (int j = 0; j < 4; ++j) acc4[i][j] = f32x4{0.f, 0.f, 0.f, 0.f};
#pragma unroll
    for (int ks = 0; ks < 5; ++ks) {
        if (ks < 4) stage_slice(Wt + 4 * (size_t)WSLOT + (ks + 1) * SLICE_G,
                                wbuf + (pb ^ 1) * BUFSZ, wv, lane);
        gemm_slice<4>(wbuf + pb * BUFSZ, actw, ks * 32 + quad * 8, lane, col, acc4);
        __syncthreads(); pb ^= 1;
    }

    // ---- scatter-add E into XCD-local Ep copy: 4 nodes x 64 B per instr ----
#pragma unroll
    for (int j = 0; j < 4; ++j) {
        const int n = j * 16 + col;
        if (n < 50) {
            const float bb = B4[n];
#pragma unroll
            for (int i = 0; i < MT; ++i)
#pragma unroll
                for (int r = 0; r < 4; ++r) {
                    const int g = tgt_s[wv * 48 + i * 16 + quad * 4 + r];
                    if (g >= 0) atomicAdd(&Epc[(size_t)g * 50 + n], acc4[i][j][r] + bb);
                }
        }
    }
}

// ---------------- Node kernel: reduce copies + fO MLP (fp32 VALU) -----------
template<int DI, int DO, bool RELU>
__device__ __forceinline__ void mlp_layer_t(
    const float* __restrict__ W, const float* __restrict__ B,
    float (*in)[64], float (*out)[64], int tid)
{
    const int et = tid & 15;
    const int jt = tid >> 4;
    constexpr int NG = (DO + 15) / 16;

    float acc0[NG], acc1[NG], acc2[NG], acc3[NG];
#pragma unroll
    for (int g = 0; g < NG; ++g) {
        const int j = jt + 16 * g;
        const float bb = (j < DO) ? B[j] : 0.f;
        acc0[g] = bb; acc1[g] = bb; acc2[g] = bb; acc3[g] = bb;
    }
    for (int k = 0; k < DI; ++k) {
        const float4 a = *(const float4*)&in[k][et * 4];
#pragma unroll
        for (int g = 0; g < NG; ++g) {
            const int j = jt + 16 * g;
            const float wv = (j < DO) ? W[k * DO + j] : 0.f;
            acc0[g] = fmaf(a.x, wv, acc0[g]);
            acc1[g] = fmaf(a.y, wv, acc1[g]);
            acc2[g] = fmaf(a.z, wv, acc2[g]);
            acc3[g] = fmaf(a.w, wv, acc3[g]);
        }
    }
#pragma unroll
    for (int g = 0; g < NG; ++g) {
        const int j = jt + 16 * g;
        if (j < DO) {
            float4 v; v.x = acc0[g]; v.y = acc1[g]; v.z = acc2[g]; v.w = acc3[g];
            if (RELU) {
                v.x = fmaxf(v.x, 0.f); v.y = fmaxf(v.y, 0.f);
                v.z = fmaxf(v.z, 0.f); v.w = fmaxf(v.w, 0.f);
            }
            *(float4*)&out[j][et * 4] = v;
        }
    }
}

__global__ __launch_bounds__(256, 2) void node_kernel(
    const float* __restrict__ Ep, int ncopies, size_t copy_elems,
    const float* __restrict__ W0, const float* __restrict__ B0,
    const float* __restrict__ W1, const float* __restrict__ B1,
    float* __restrict__ P, int n_nodes)
{
    __shared__ float bufA[104][64];
    __shared__ float bufB[104][64];
    const int tid = threadIdx.x;
    const int n0  = blockIdx.x * 64;

    for (int idx = tid; idx < 64 * 50; idx += 256) {
        const int e = idx / 50;
        const int k = idx - e * 50;
        const int n = n0 + e;
        float s = 0.f;
        if (n < n_nodes) {
            const float* p = &Ep[(size_t)n * 50 + k];
            for (int c = 0; c < ncopies; ++c) s += p[(size_t)c * copy_elems];
        }
        bufA[k][e] = s;
    }
    __syncthreads();
    mlp_layer_t<50, 100, true >(W0, B0, bufA, bufB, tid); __syncthreads();
    mlp_layer_t<100, 4, false>(W1, B1, bufB, bufA, tid); __syncthreads();
    for (int idx = tid; idx < 64 * 4; idx += 256) {
        const int e = idx & 63;
        const int j = idx >> 6;
        const int n = n0 + e;
        if (n < n_nodes) P[(size_t)n * 4 + j] = bufA[j][e];
    }
}

// ------------------------------- launcher -----------------------------------
extern "C" void kernel_launch(void* const* d_in, const int* in_sizes, int n_in,
                              void* d_out, int out_size, void* d_ws, size_t ws_size,
                              hipStream_t stream)
{
    const float* t   = (const float*)d_in[0];
    const float* x   = (const float*)d_in[1];
    const float* Ofx = (const float*)d_in[2];
    const int*   src = (const int*)d_in[3];
    const int*   tgt = (const int*)d_in[4];
    const float* W0  = (const float*)d_in[5];  const float* B0 = (const float*)d_in[6];
    const float* W1  = (const float*)d_in[7];  const float* B1 = (const float*)d_in[8];
    const float* W2  = (const float*)d_in[9];  const float* B2 = (const float*)d_in[10];
    const float* W3  = (const float*)d_in[11]; const float* B3 = (const float*)d_in[12];
    const float* W4  = (const float*)d_in[13]; const float* B4 = (const float*)d_in[14];
    const float* OW0 = (const float*)d_in[15]; const float* OB0 = (const float*)d_in[16];
    const float* OW1 = (const float*)d_in[17]; const float* OB1 = (const float*)d_in[18];

    const int n_nodes = in_sizes[1] / 4;
    const int n_edges = in_sizes[3];

    u16*   Wt = (u16*)d_ws;                                // 5*51200 = 256000 B
    float* Ep = (float*)((char*)d_ws + 262144);            // ncopies x [N,50] fp32

    const size_t copy_elems = (size_t)n_nodes * 50;
    const size_t avail = (ws_size > 262144) ? ws_size - 262144 : 0;
    int ncopies = 1;                                        // power of two, <= 4
    while (ncopies * 2 <= 4 &&
           (size_t)(ncopies * 2) * copy_elems * sizeof(float) <= avail)
        ncopies *= 2;
    const int copy_mask = ncopies - 1;

    prep_weights<<<dim3(32, 5), 256, 0, stream>>>(W0, W1, W2, W3, W4, Wt);
    hipMemsetAsync(Ep, 0, (size_t)ncopies * copy_elems * sizeof(float), stream);

    edge_kernel<<<(n_edges + BLK_E - 1) / BLK_E, NTHR, 0, stream>>>(
        t, x, Ofx, src, tgt, Wt, B0, B1, B2, B3, B4,
        Ep, n_edges, copy_mask, copy_elems);

    node_kernel<<<(n_nodes + 63) / 64, 256, 0, stream>>>(
        Ep, ncopies, copy_elems, OW0, OB0, OW1, OB1, (float*)d_out, n_nodes);
}

// Round 10
// 1105.276 us; speedup vs baseline: 1.3901x; 1.1523x over previous
//
#include <hip/hip_runtime.h>

typedef unsigned short u16;
typedef __attribute__((ext_vector_type(8))) short short8;
typedef __attribute__((ext_vector_type(4))) float f32x4;

constexpr int SA     = 168;   // act row stride (bf16): 336 B, 16B-aligned, 2-way banks
constexpr int BLK_E  = 96;    // edges per block
constexpr int NTHR   = 192;   // 3 waves, each owns 32 edges (MT=2)
constexpr int MT     = 2;     // M-tiles per wave
constexpr int J_MAX  = 10;    // N tiles (160 padded)
constexpr int KS_MAX = 5;     // K slices of 32 (160 padded)
constexpr int CHUNK  = 512;   // u16 elems per (j) fragment chunk = 1 KB
constexpr int NCHB   = 10;    // chunks per LDS slice buffer (exact)
constexpr int BUFSZ  = NCHB * CHUNK;             // 5120 elems per buffer
constexpr int SLICE_G = J_MAX * CHUNK;           // 5120 elems per global slice
constexpr int WSLOT  = KS_MAX * SLICE_G;         // 25600 elems per layer

typedef __attribute__((address_space(1))) const unsigned int gu32;
typedef __attribute__((address_space(3))) unsigned int lu32;

__device__ __forceinline__ void gload_lds16(const u16* g, u16* l) {
    // 16B per lane; LDS dest = wave-uniform base + lane*16 (HW scatter)
    __builtin_amdgcn_global_load_lds((gu32*)g, (lu32*)l, 16, 0, 0);
}

__device__ __forceinline__ u16 f2bf(float f) {  // RNE f32->bf16
    union { float f; unsigned u; } c; c.f = f;
    return (u16)((c.u + 0x7fffu + ((c.u >> 16) & 1u)) >> 16);
}

// activation k-storage permutation (hidden layers):
//  logical n = j*16+col stored at k' = col*8+j (j<8) | 128+col*2+(j-8) (j=8,9)
__device__ __forceinline__ int kperm(int kp) {
    if (kp < 128) return (kp & 7) * 16 + (kp >> 3);
    if (kp < 160) { const int m = kp - 128; return (8 + (m & 1)) * 16 + (m >> 1); }
    return 1 << 30;
}

// ---- prep: weights -> slice-major MFMA fragment order ----------------------
__global__ void prep_weights(const float* __restrict__ W0, const float* __restrict__ W1,
                             const float* __restrict__ W2, const float* __restrict__ W3,
                             const float* __restrict__ W4, u16* __restrict__ out)
{
    const int l = blockIdx.y;
    const float* W; int DI, DO; bool perm;
    if      (l == 0) { W = W0; DI = 13;  DO = 150; perm = false; }
    else if (l == 1) { W = W1; DI = 150; DO = 150; perm = true;  }
    else if (l == 2) { W = W2; DI = 150; DO = 150; perm = true;  }
    else if (l == 3) { W = W3; DI = 150; DO = 150; perm = true;  }
    else             { W = W4; DI = 150; DO = 50;  perm = true;  }
    u16* dst = out + (size_t)l * WSLOT;
    for (int idx = blockIdx.x * blockDim.x + threadIdx.x; idx < WSLOT;
         idx += gridDim.x * blockDim.x) {
        const int chunk = idx / CHUNK;            // = ks*J_MAX + j
        const int within = idx - chunk * CHUNK;
        const int lane = within >> 3, e = within & 7;
        const int ks = chunk / J_MAX, j = chunk - ks * J_MAX;
        const int c = lane & 15, q = lane >> 4;
        const int n = j * 16 + c;
        const int kphys = ks * 32 + q * 8 + e;
        const int klog = perm ? kperm(kphys) : kphys;
        const float v = (n < DO && klog < DI) ? W[klog * DO + n] : 0.f;
        dst[idx] = f2bf(v);
    }
}

// ---- async stage one 10-chunk slice: 3 waves stage 4/3/3 chunks ------------
__device__ __forceinline__ void stage_slice(const u16* __restrict__ gslice,
                                            u16* lbuf, int wv, int lane) {
#pragma unroll
    for (int k = 0; k < 4; ++k) {
        const int c = wv + 3 * k;                  // wave0:0,3,6,9 w1:1,4,7 w2:2,5,8
        if (c < 10)
            gload_lds16(gslice + c * CHUNK + lane * 8, lbuf + c * CHUNK);
    }
}

// ---- one K-slice of MFMA: A from act LDS, B from staged slice buffer -------
template<int NT>
__device__ __forceinline__ void gemm_slice(const u16* wb, const u16* actw, int koff,
        int lane, int col, f32x4 (&acc)[MT][NT])
{
    short8 Af[MT];
#pragma unroll
    for (int i = 0; i < MT; ++i)
        Af[i] = *(const short8*)&actw[(i * 16 + col) * SA + koff];
#pragma unroll
    for (int j = 0; j < NT; ++j) {
        const short8 Bf = *(const short8*)&wb[j * CHUNK + lane * 8];
#pragma unroll
        for (int i = 0; i < MT; ++i)
            acc[i][j] = __builtin_amdgcn_mfma_f32_16x16x32_bf16(Af[i], Bf, acc[i][j], 0, 0, 0);
    }
}

// ---- epilogue: bias+relu+bf16, k-permuted in-place store (b128 + b32) ------
__device__ __forceinline__ void epilogue(
    u16* actw, const float* __restrict__ bias,
    int col, int quad, f32x4 (&acc)[MT][10])
{
    float bb[10];
#pragma unroll
    for (int j = 0; j < 10; ++j) {
        const int n = j * 16 + col;
        bb[j] = (n < 150) ? bias[n] : 0.f;
    }
#pragma unroll
    for (int i = 0; i < MT; ++i)
#pragma unroll
        for (int r = 0; r < 4; ++r) {
            u16* row = &actw[(i * 16 + quad * 4 + r) * SA];
            short8 pk;
#pragma unroll
            for (int j = 0; j < 8; ++j)
                pk[j] = (short)f2bf(fmaxf(acc[i][j][r] + bb[j], 0.f));
            *(short8*)&row[col * 8] = pk;                          // k' = col*8 + j
            const u16 lo = f2bf(fmaxf(acc[i][8][r] + bb[8], 0.f));
            const u16 hi = f2bf(fmaxf(acc[i][9][r] + bb[9], 0.f));
            *(unsigned*)&row[128 + col * 2] =                      // k' = 128+col*2+(j-8)
                (unsigned)lo | ((unsigned)hi << 16);
        }
}

// ------------------------------- Edge kernel --------------------------------
// 3 waves x 32 edges (MT=2); act slabs wave-private after the first barrier.
// Weight slices double-buffered in LDS via async global_load_lds; one
// __syncthreads per slice AFTER compute drains the next slice's staging.
// LDS = 53120 B -> 3 blocks/CU = 9 waves/CU in 3 independent barrier groups.
__global__ __launch_bounds__(NTHR, 3) void edge_kernel(
    const float* __restrict__ t, const float* __restrict__ x, const float* __restrict__ Ofx,
    const int* __restrict__ src, const int* __restrict__ tgt,
    const u16* __restrict__ Wt,
    const float* __restrict__ B0, const float* __restrict__ B1, const float* __restrict__ B2,
    const float* __restrict__ B3, const float* __restrict__ B4,
    float* __restrict__ Ep, int n_edges, int copy_mask, size_t copy_elems)
{
    __shared__ __align__(16) u16 act[BLK_E * SA];      // 32256 B
    __shared__ __align__(16) u16 wbuf[2 * BUFSZ];      // 20480 B
    __shared__ int tgt_s[BLK_E];                       // 384 B  -> 53120 B total

    const int tid  = threadIdx.x;
    const int lane = tid & 63;
    const int wv   = tid >> 6;
    const int col  = lane & 15;
    const int quad = lane >> 4;

    const int xcd = (int)(__builtin_amdgcn_s_getreg(6164) & 7u) & copy_mask;
    float* __restrict__ Epc = Ep + (size_t)xcd * copy_elems;

    // ---- gather R' (all threads; visible to all waves after first barrier) --
    if (tid < BLK_E) {
        const int e = tid;
        const long long ge = (long long)blockIdx.x * BLK_E + e;
        const bool valid = ge < n_edges;
        const int s = valid ? src[ge] : 0;
        const int g = valid ? tgt[ge] : 0;
        float v[16];
        const float4 xs = valid ? *(const float4*)&x[(size_t)s * 4] : float4{0, 0, 0, 0};
        const float2 os = valid ? *(const float2*)&Ofx[(size_t)s * 2] : float2{0, 0};
        const float4 xg = valid ? *(const float4*)&x[(size_t)g * 4] : float4{0, 0, 0, 0};
        const float2 og = valid ? *(const float2*)&Ofx[(size_t)g * 2] : float2{0, 0};
        v[0] = xs.x; v[1] = xs.y; v[2] = xs.z; v[3] = xs.w; v[4] = os.x; v[5] = os.y;
        v[6] = xg.x; v[7] = xg.y; v[8] = xg.z; v[9] = xg.w; v[10] = og.x; v[11] = og.y;
        v[12] = valid ? t[0] : 0.f; v[13] = v[14] = v[15] = 0.f;
        short8 c0, c1;
#pragma unroll
        for (int k = 0; k < 8; ++k) { c0[k] = (short)f2bf(v[k]); c1[k] = (short)f2bf(v[k + 8]); }
        u16* row = &act[e * SA];
        *(short8*)&row[0]  = c0;
        *(short8*)&row[8]  = c1;
        *(short8*)&row[16] = short8{0, 0, 0, 0, 0, 0, 0, 0};
        *(short8*)&row[24] = short8{0, 0, 0, 0, 0, 0, 0, 0};
        tgt_s[e] = valid ? g : -1;
    }

    u16* actw = act + wv * 32 * SA;     // this wave's private 32 rows
    const float* Bs[4] = {B0, B1, B2, B3};

    // ---- slice pipeline: stage(s+1) -> compute(s) -> barrier (drains s+1) --
    stage_slice(Wt, wbuf, wv, lane);                        // s=0: (L0,ks0)
    __syncthreads();                                        // drain stage(0)+gather

    f32x4 acc[MT][10];
    int pb = 0;

    // L0 (1 slice)
    stage_slice(Wt + 1 * WSLOT, wbuf + BUFSZ, wv, lane);    // s=1: (L1,ks0)
#pragma unroll
    for (int i = 0; i < MT; ++i)
#pragma unroll
        for (int j = 0; j < 10; ++j) acc[i][j] = f32x4{0.f, 0.f, 0.f, 0.f};
    gemm_slice<10>(wbuf + pb * BUFSZ, actw, quad * 8, lane, col, acc);
    epilogue(actw, B0, col, quad, acc);
    __syncthreads(); pb ^= 1;

    // L1..L3 (5 slices each)
    for (int l = 1; l <= 3; ++l) {
#pragma unroll
        for (int i = 0; i < MT; ++i)
#pragma unroll
            for (int j = 0; j < 10; ++j) acc[i][j] = f32x4{0.f, 0.f, 0.f, 0.f};
#pragma unroll
        for (int ks = 0; ks < 5; ++ks) {
            const u16* nxt = (ks < 4) ? (Wt + (size_t)l * WSLOT + (ks + 1) * SLICE_G)
                                      : (Wt + (size_t)(l + 1) * WSLOT);
            stage_slice(nxt, wbuf + (pb ^ 1) * BUFSZ, wv, lane);
            gemm_slice<10>(wbuf + pb * BUFSZ, actw, ks * 32 + quad * 8, lane, col, acc);
            if (ks == 4) epilogue(actw, Bs[l], col, quad, acc);
            __syncthreads(); pb ^= 1;
        }
    }

    // L4 (5 slices, NT=4, linear) then scatter
    f32x4 acc4[MT][4];
#pragma unroll
    for (int i = 0; i < MT; ++i)
#pragma unroll
        for (int j = 0; j < 4; ++j) acc4[i][j] = f32x4{0.f, 0.f, 0.f, 0.f};
#pragma unroll
    for (int ks = 0; ks < 5; ++ks) {
        if (ks < 4) stage_slice(Wt + 4 * (size_t)WSLOT + (ks + 1) * SLICE_G,
                                wbuf + (pb ^ 1) * BUFSZ, wv, lane);
        gemm_slice<4>(wbuf + pb * BUFSZ, actw, ks * 32 + quad * 8, lane, col, acc4);
        __syncthreads(); pb ^= 1;
    }

    // ---- scatter-add E into XCD-local Ep copy: 4 nodes x 64 B per instr ----
#pragma unroll
    for (int j = 0; j < 4; ++j) {
        const int n = j * 16 + col;
        if (n < 50) {
            const float bb = B4[n];
#pragma unroll
            for (int i = 0; i < MT; ++i)
#pragma unroll
                for (int r = 0; r < 4; ++r) {
                    const int g = tgt_s[wv * 32 + i * 16 + quad * 4 + r];
                    if (g >= 0) atomicAdd(&Epc[(size_t)g * 50 + n], acc4[i][j][r] + bb);
                }
        }
    }
}

// ---------------- Node kernel: reduce copies + fO MLP (fp32 VALU) -----------
template<int DI, int DO, bool RELU>
__device__ __forceinline__ void mlp_layer_t(
    const float* __restrict__ W, const float* __restrict__ B,
    float (*in)[64], float (*out)[64], int tid)
{
    const int et = tid & 15;
    const int jt = tid >> 4;
    constexpr int NG = (DO + 15) / 16;

    float acc0[NG], acc1[NG], acc2[NG], acc3[NG];
#pragma unroll
    for (int g = 0; g < NG; ++g) {
        const int j = jt + 16 * g;
        const float bb = (j < DO) ? B[j] : 0.f;
        acc0[g] = bb; acc1[g] = bb; acc2[g] = bb; acc3[g] = bb;
    }
    for (int k = 0; k < DI; ++k) {
        const float4 a = *(const float4*)&in[k][et * 4];
#pragma unroll
        for (int g = 0; g < NG; ++g) {
            const int j = jt + 16 * g;
            const float wv = (j < DO) ? W[k * DO + j] : 0.f;
            acc0[g] = fmaf(a.x, wv, acc0[g]);
            acc1[g] = fmaf(a.y, wv, acc1[g]);
            acc2[g] = fmaf(a.z, wv, acc2[g]);
            acc3[g] = fmaf(a.w, wv, acc3[g]);
        }
    }
#pragma unroll
    for (int g = 0; g < NG; ++g) {
        const int j = jt + 16 * g;
        if (j < DO) {
            float4 v; v.x = acc0[g]; v.y = acc1[g]; v.z = acc2[g]; v.w = acc3[g];
            if (RELU) {
                v.x = fmaxf(v.x, 0.f); v.y = fmaxf(v.y, 0.f);
                v.z = fmaxf(v.z, 0.f); v.w = fmaxf(v.w, 0.f);
            }
            *(float4*)&out[j][et * 4] = v;
        }
    }
}

__global__ __launch_bounds__(256, 2) void node_kernel(
    const float* __restrict__ Ep, int ncopies, size_t copy_elems,
    const float* __restrict__ W0, const float* __restrict__ B0,
    const float* __restrict__ W1, const float* __restrict__ B1,
    float* __restrict__ P, int n_nodes)
{
    __shared__ float bufA[104][64];
    __shared__ float bufB[104][64];
    const int tid = threadIdx.x;
    const int n0  = blockIdx.x * 64;

    for (int idx = tid; idx < 64 * 50; idx += 256) {
        const int e = idx / 50;
        const int k = idx - e * 50;
        const int n = n0 + e;
        float s = 0.f;
        if (n < n_nodes) {
            const float* p = &Ep[(size_t)n * 50 + k];
            for (int c = 0; c < ncopies; ++c) s += p[(size_t)c * copy_elems];
        }
        bufA[k][e] = s;
    }
    __syncthreads();
    mlp_layer_t<50, 100, true >(W0, B0, bufA, bufB, tid); __syncthreads();
    mlp_layer_t<100, 4, false>(W1, B1, bufB, bufA, tid); __syncthreads();
    for (int idx = tid; idx < 64 * 4; idx += 256) {
        const int e = idx & 63;
        const int j = idx >> 6;
        const int n = n0 + e;
        if (n < n_nodes) P[(size_t)n * 4 + j] = bufA[j][e];
    }
}

// ------------------------------- launcher -----------------------------------
extern "C" void kernel_launch(void* const* d_in, const int* in_sizes, int n_in,
                              void* d_out, int out_size, void* d_ws, size_t ws_size,
                              hipStream_t stream)
{
    const float* t   = (const float*)d_in[0];
    const float* x   = (const float*)d_in[1];
    const float* Ofx = (const float*)d_in[2];
    const int*   src = (const int*)d_in[3];
    const int*   tgt = (const int*)d_in[4];
    const float* W0  = (const float*)d_in[5];  const float* B0 = (const float*)d_in[6];
    const float* W1  = (const float*)d_in[7];  const float* B1 = (const float*)d_in[8];
    const float* W2  = (const float*)d_in[9];  const float* B2 = (const float*)d_in[10];
    const float* W3  = (const float*)d_in[11]; const float* B3 = (const float*)d_in[12];
    const float* W4  = (const float*)d_in[13]; const float* B4 = (const float*)d_in[14];
    const float* OW0 = (const float*)d_in[15]; const float* OB0 = (const float*)d_in[16];
    const float* OW1 = (const float*)d_in[17]; const float* OB1 = (const float*)d_in[18];

    const int n_nodes = in_sizes[1] / 4;
    const int n_edges = in_sizes[3];

    u16*   Wt = (u16*)d_ws;                                // 5*51200 = 256000 B
    float* Ep = (float*)((char*)d_ws + 262144);            // ncopies x [N,50] fp32

    const size_t copy_elems = (size_t)n_nodes * 50;
    const size_t avail = (ws_size > 262144) ? ws_size - 262144 : 0;
    int ncopies = 1;                                        // power of two, <= 4
    while (ncopies * 2 <= 4 &&
           (size_t)(ncopies * 2) * copy_elems * sizeof(float) <= avail)
        ncopies *= 2;
    const int copy_mask = ncopies - 1;

    prep_weights<<<dim3(32, 5), 256, 0, stream>>>(W0, W1, W2, W3, W4, Wt);
    hipMemsetAsync(Ep, 0, (size_t)ncopies * copy_elems * sizeof(float), stream);

    edge_kernel<<<(n_edges + BLK_E - 1) / BLK_E, NTHR, 0, stream>>>(
        t, x, Ofx, src, tgt, Wt, B0, B1, B2, B3, B4,
        Ep, n_edges, copy_mask, copy_elems);

    node_kernel<<<(n_nodes + 63) / 64, 256, 0, stream>>>(
        Ep, ncopies, copy_elems, OW0, OB0, OW1, OB1, (float*)d_out, n_nodes);
}

// Round 11
// 1081.822 us; speedup vs baseline: 1.4202x; 1.0217x over previous
//
#include <hip/hip_runtime.h>
#include <hip/hip_bf16.h>

typedef unsigned short u16;
typedef __attribute__((ext_vector_type(8))) short short8;
typedef __attribute__((ext_vector_type(4))) float f32x4;

constexpr int SA     = 168;   // act row stride (bf16): 336 B, 16B-aligned, 2-way banks
constexpr int BLK_E  = 96;    // edges per block
constexpr int NTHR   = 192;   // 3 waves, each owns 32 edges (MT=2)
constexpr int MT     = 2;     // M-tiles per wave
constexpr int J_MAX  = 10;    // N tiles (160 padded)
constexpr int KS_MAX = 5;     // K slices of 32 (160 padded)
constexpr int CHUNK  = 512;   // u16 elems per (j) fragment chunk = 1 KB
constexpr int NCHB   = 10;    // chunks per LDS slice buffer (exact)
constexpr int BUFSZ  = NCHB * CHUNK;             // 5120 elems per buffer
constexpr int SLICE_G = J_MAX * CHUNK;           // 5120 elems per global slice
constexpr int WSLOT  = KS_MAX * SLICE_G;         // 25600 elems per layer
constexpr int WT_BYTES = 5 * WSLOT * 2;          // 256000 B weights
constexpr int WS_HDR   = 262144;                 // header region (weights+bias)

typedef __attribute__((address_space(1))) const unsigned int gu32;
typedef __attribute__((address_space(3))) unsigned int lu32;

__device__ __forceinline__ void gload_lds16(const u16* g, u16* l) {
    __builtin_amdgcn_global_load_lds((gu32*)g, (lu32*)l, 16, 0, 0);
}

__device__ __forceinline__ u16 f2bf(float f) {  // RNE f32->bf16 (prep only)
    union { float f; unsigned u; } c; c.f = f;
    return (u16)((c.u + 0x7fffu + ((c.u >> 16) & 1u)) >> 16);
}

// packed RNE f32x2 -> bf16x2 (v_cvt_pk_bf16_f32 on gfx950)
__device__ __forceinline__ unsigned pk_bf16(float a, float b) {
    float2 f; f.x = a; f.y = b;
    __hip_bfloat162 h = __float22bfloat162_rn(f);
    return *(unsigned*)&h;
}

// activation k-storage permutation (hidden layers):
//  logical n = j*16+col stored at k' = col*8+j (j<8) | 128+col*2+(j-8) (j=8,9)
__device__ __forceinline__ int kperm(int kp) {
    if (kp < 128) return (kp & 7) * 16 + (kp >> 3);
    if (kp < 160) { const int m = kp - 128; return (8 + (m & 1)) * 16 + (m >> 1); }
    return 1 << 30;
}

// ---- prep: weights -> slice-major MFMA fragment order ----------------------
__global__ void prep_weights(const float* __restrict__ W0, const float* __restrict__ W1,
                             const float* __restrict__ W2, const float* __restrict__ W3,
                             const float* __restrict__ W4, u16* __restrict__ out)
{
    const int l = blockIdx.y;
    const float* W; int DI, DO; bool perm;
    if      (l == 0) { W = W0; DI = 13;  DO = 150; perm = false; }
    else if (l == 1) { W = W1; DI = 150; DO = 150; perm = true;  }
    else if (l == 2) { W = W2; DI = 150; DO = 150; perm = true;  }
    else if (l == 3) { W = W3; DI = 150; DO = 150; perm = true;  }
    else             { W = W4; DI = 150; DO = 50;  perm = true;  }
    u16* dst = out + (size_t)l * WSLOT;
    for (int idx = blockIdx.x * blockDim.x + threadIdx.x; idx < WSLOT;
         idx += gridDim.x * blockDim.x) {
        const int chunk = idx / CHUNK;            // = ks*J_MAX + j
        const int within = idx - chunk * CHUNK;
        const int lane = within >> 3, e = within & 7;
        const int ks = chunk / J_MAX, j = chunk - ks * J_MAX;
        const int c = lane & 15, q = lane >> 4;
        const int n = j * 16 + c;
        const int kphys = ks * 32 + q * 8 + e;
        const int klog = perm ? kperm(kphys) : kphys;
        const float v = (n < DO && klog < DI) ? W[klog * DO + n] : 0.f;
        dst[idx] = f2bf(v);
    }
}

// ---- prep: zero-padded biases, 5 x 160 floats ------------------------------
__global__ void prep_bias(const float* __restrict__ B0, const float* __restrict__ B1,
                          const float* __restrict__ B2, const float* __restrict__ B3,
                          const float* __restrict__ B4, float* __restrict__ out)
{
    const int idx = blockIdx.x * blockDim.x + threadIdx.x;
    if (idx >= 800) return;
    const int l = idx / 160, j = idx - l * 160;
    const float* B; int DO;
    if      (l == 0) { B = B0; DO = 150; }
    else if (l == 1) { B = B1; DO = 150; }
    else if (l == 2) { B = B2; DO = 150; }
    else if (l == 3) { B = B3; DO = 150; }
    else             { B = B4; DO = 50;  }
    out[idx] = (j < DO) ? B[j] : 0.f;
}

// ---- async stage one 10-chunk slice: 3 waves stage 4/3/3 chunks ------------
__device__ __forceinline__ void stage_slice(const u16* __restrict__ gslice,
                                            u16* lbuf, int wv, int lane) {
#pragma unroll
    for (int k = 0; k < 4; ++k) {
        const int c = wv + 3 * k;                  // wave0:0,3,6,9 w1:1,4,7 w2:2,5,8
        if (c < 10)
            gload_lds16(gslice + c * CHUNK + lane * 8, lbuf + c * CHUNK);
    }
}

// ---- A-fragment load (wave-private act slab) -------------------------------
__device__ __forceinline__ void loadA(const u16* actw, int koff, int col,
                                      short8 (&Af)[MT]) {
#pragma unroll
    for (int i = 0; i < MT; ++i)
        Af[i] = *(const short8*)&actw[(i * 16 + col) * SA + koff];
}

// ---- one K-slice of MFMA: A preloaded, B from staged slice buffer ----------
template<int NT>
__device__ __forceinline__ void gemm_slice(const u16* wb, const short8 (&Af)[MT],
        int lane, f32x4 (&acc)[MT][NT])
{
#pragma unroll
    for (int j = 0; j < NT; ++j) {
        const short8 Bf = *(const short8*)&wb[j * CHUNK + lane * 8];
#pragma unroll
        for (int i = 0; i < MT; ++i)
            acc[i][j] = __builtin_amdgcn_mfma_f32_16x16x32_bf16(Af[i], Bf, acc[i][j], 0, 0, 0);
    }
}

// ---- epilogue: bias+relu + packed bf16 cvt, k-permuted in-place store ------
__device__ __forceinline__ void epilogue(
    u16* actw, const float* __restrict__ bias,   // padded [160]
    int col, int quad, f32x4 (&acc)[MT][10])
{
    float bb[10];
#pragma unroll
    for (int j = 0; j < 10; ++j) bb[j] = bias[j * 16 + col];
#pragma unroll
    for (int i = 0; i < MT; ++i)
#pragma unroll
        for (int r = 0; r < 4; ++r) {
            u16* row = &actw[(i * 16 + quad * 4 + r) * SA];
            uint4 pk;
            pk.x = pk_bf16(fmaxf(acc[i][0][r] + bb[0], 0.f),
                           fmaxf(acc[i][1][r] + bb[1], 0.f));
            pk.y = pk_bf16(fmaxf(acc[i][2][r] + bb[2], 0.f),
                           fmaxf(acc[i][3][r] + bb[3], 0.f));
            pk.z = pk_bf16(fmaxf(acc[i][4][r] + bb[4], 0.f),
                           fmaxf(acc[i][5][r] + bb[5], 0.f));
            pk.w = pk_bf16(fmaxf(acc[i][6][r] + bb[6], 0.f),
                           fmaxf(acc[i][7][r] + bb[7], 0.f));
            *(uint4*)&row[col * 8] = pk;                          // k' = col*8 + j
            *(unsigned*)&row[128 + col * 2] =                      // k' = 128+col*2+(j-8)
                pk_bf16(fmaxf(acc[i][8][r] + bb[8], 0.f),
                        fmaxf(acc[i][9][r] + bb[9], 0.f));
        }
}

// ------------------------------- Edge kernel --------------------------------
// 3 waves x 32 edges (MT=2); act slabs wave-private after the first barrier.
// Weight slices double-buffered via async global_load_lds; A-frags software-
// prefetched across the barrier (wave-private); one __syncthreads per slice.
// LDS = 53120 B -> 3 blocks/CU = 9 waves/CU in 3 independent barrier groups.
__global__ __launch_bounds__(NTHR, 3) void edge_kernel(
    const float* __restrict__ t, const float* __restrict__ x, const float* __restrict__ Ofx,
    const int* __restrict__ src, const int* __restrict__ tgt,
    const u16* __restrict__ Wt, const float* __restrict__ Bp,
    float* __restrict__ Ep, int n_edges, int copy_mask, size_t copy_elems)
{
    __shared__ __align__(16) u16 act[BLK_E * SA];      // 32256 B
    __shared__ __align__(16) u16 wbuf[2 * BUFSZ];      // 20480 B
    __shared__ int tgt_s[BLK_E];                       // 384 B  -> 53120 B total

    const int tid  = threadIdx.x;
    const int lane = tid & 63;
    const int wv   = tid >> 6;
    const int col  = lane & 15;
    const int quad = lane >> 4;

    const int xcd = (int)(__builtin_amdgcn_s_getreg(6164) & 7u) & copy_mask;
    float* __restrict__ Epc = Ep + (size_t)xcd * copy_elems;

    // ---- gather R' (all threads; visible to all waves after first barrier) --
    if (tid < BLK_E) {
        const int e = tid;
        const long long ge = (long long)blockIdx.x * BLK_E + e;
        const bool valid = ge < n_edges;
        const int s = valid ? src[ge] : 0;
        const int g = valid ? tgt[ge] : 0;
        const float4 xs = valid ? *(const float4*)&x[(size_t)s * 4] : float4{0, 0, 0, 0};
        const float2 os = valid ? *(const float2*)&Ofx[(size_t)s * 2] : float2{0, 0};
        const float4 xg = valid ? *(const float4*)&x[(size_t)g * 4] : float4{0, 0, 0, 0};
        const float2 og = valid ? *(const float2*)&Ofx[(size_t)g * 2] : float2{0, 0};
        const float tv = valid ? t[0] : 0.f;
        uint4 w0, w1;
        w0.x = pk_bf16(xs.x, xs.y); w0.y = pk_bf16(xs.z, xs.w);
        w0.z = pk_bf16(os.x, os.y); w0.w = pk_bf16(xg.x, xg.y);
        w1.x = pk_bf16(xg.z, xg.w); w1.y = pk_bf16(og.x, og.y);
        w1.z = pk_bf16(tv, 0.f);    w1.w = 0u;
        u16* row = &act[e * SA];
        *(uint4*)&row[0]  = w0;
        *(uint4*)&row[8]  = w1;
        *(uint4*)&row[16] = uint4{0, 0, 0, 0};
        *(uint4*)&row[24] = uint4{0, 0, 0, 0};
        tgt_s[e] = valid ? g : -1;
    }

    u16* actw = act + wv * 32 * SA;     // this wave's private 32 rows

    // ---- slice pipeline: stage(s+1) -> compute(s) -> barrier (drains s+1) --
    stage_slice(Wt, wbuf, wv, lane);                        // s=0: (L0,ks0)
    __syncthreads();                                        // drain stage(0)+gather

    f32x4 acc[MT][10];
    short8 Af[MT], Afn[MT];
    int pb = 0;

    // L0 (1 slice)
    stage_slice(Wt + WSLOT, wbuf + BUFSZ, wv, lane);        // s=1: (L1,ks0)
#pragma unroll
    for (int i = 0; i < MT; ++i)
#pragma unroll
        for (int j = 0; j < 10; ++j) acc[i][j] = f32x4{0.f, 0.f, 0.f, 0.f};
    loadA(actw, quad * 8, col, Af);
    gemm_slice<10>(wbuf, Af, lane, acc);
    epilogue(actw, Bp, col, quad, acc);
    loadA(actw, quad * 8, col, Af);                         // L1 ks0 (post-epi, pre-barrier)
    __syncthreads(); pb ^= 1;

    // L1..L3 (5 slices each)
    for (int l = 1; l <= 3; ++l) {
#pragma unroll
        for (int i = 0; i < MT; ++i)
#pragma unroll
            for (int j = 0; j < 10; ++j) acc[i][j] = f32x4{0.f, 0.f, 0.f, 0.f};
#pragma unroll
        for (int ks = 0; ks < 5; ++ks) {
            const u16* nxt = (ks < 4) ? (Wt + (size_t)l * WSLOT + (ks + 1) * SLICE_G)
                                      : (Wt + (size_t)(l + 1) * WSLOT);
            stage_slice(nxt, wbuf + (pb ^ 1) * BUFSZ, wv, lane);
            if (ks < 4) loadA(actw, (ks + 1) * 32 + quad * 8, col, Afn);  // A-prefetch
            gemm_slice<10>(wbuf + pb * BUFSZ, Af, lane, acc);
            if (ks == 4) {
                epilogue(actw, Bp + l * 160, col, quad, acc);
                loadA(actw, quad * 8, col, Af);             // next layer ks0
            } else {
#pragma unroll
                for (int i = 0; i < MT; ++i) Af[i] = Afn[i];
            }
            __syncthreads(); pb ^= 1;
        }
    }

    // L4 (5 slices, NT=4, linear) then scatter
    f32x4 acc4[MT][4];
#pragma unroll
    for (int i = 0; i < MT; ++i)
#pragma unroll
        for (int j = 0; j < 4; ++j) acc4[i][j] = f32x4{0.f, 0.f, 0.f, 0.f};
#pragma unroll
    for (int ks = 0; ks < 5; ++ks) {
        if (ks < 4) {
            stage_slice(Wt + 4 * (size_t)WSLOT + (ks + 1) * SLICE_G,
                        wbuf + (pb ^ 1) * BUFSZ, wv, lane);
            loadA(actw, (ks + 1) * 32 + quad * 8, col, Afn);
        }
        gemm_slice<4>(wbuf + pb * BUFSZ, Af, lane, acc4);
        __syncthreads(); pb ^= 1;
        if (ks < 4) {
#pragma unroll
            for (int i = 0; i < MT; ++i) Af[i] = Afn[i];
        }
    }

    // ---- scatter-add E into XCD-local Ep copy: 4 nodes x 64 B per instr ----
    const float* B4p = Bp + 4 * 160;
#pragma unroll
    for (int j = 0; j < 4; ++j) {
        const int n = j * 16 + col;
        if (n < 50) {
            const float bb = B4p[n];
#pragma unroll
            for (int i = 0; i < MT; ++i)
#pragma unroll
                for (int r = 0; r < 4; ++r) {
                    const int g = tgt_s[wv * 32 + i * 16 + quad * 4 + r];
                    if (g >= 0) atomicAdd(&Epc[(size_t)g * 50 + n], acc4[i][j][r] + bb);
                }
        }
    }
}

// ---------------- Node kernel: reduce copies + fO MLP (fp32 VALU) -----------
template<int DI, int DO, bool RELU>
__device__ __forceinline__ void mlp_layer_t(
    const float* __restrict__ W, const float* __restrict__ B,
    float (*in)[64], float (*out)[64], int tid)
{
    const int et = tid & 15;
    const int jt = tid >> 4;
    constexpr int NG = (DO + 15) / 16;

    float acc0[NG], acc1[NG], acc2[NG], acc3[NG];
#pragma unroll
    for (int g = 0; g < NG; ++g) {
        const int j = jt + 16 * g;
        const float bb = (j < DO) ? B[j] : 0.f;
        acc0[g] = bb; acc1[g] = bb; acc2[g] = bb; acc3[g] = bb;
    }
    for (int k = 0; k < DI; ++k) {
        const float4 a = *(const float4*)&in[k][et * 4];
#pragma unroll
        for (int g = 0; g < NG; ++g) {
            const int j = jt + 16 * g;
            const float wv = (j < DO) ? W[k * DO + j] : 0.f;
            acc0[g] = fmaf(a.x, wv, acc0[g]);
            acc1[g] = fmaf(a.y, wv, acc1[g]);
            acc2[g] = fmaf(a.z, wv, acc2[g]);
            acc3[g] = fmaf(a.w, wv, acc3[g]);
        }
    }
#pragma unroll
    for (int g = 0; g < NG; ++g) {
        const int j = jt + 16 * g;
        if (j < DO) {
            float4 v; v.x = acc0[g]; v.y = acc1[g]; v.z = acc2[g]; v.w = acc3[g];
            if (RELU) {
                v.x = fmaxf(v.x, 0.f); v.y = fmaxf(v.y, 0.f);
                v.z = fmaxf(v.z, 0.f); v.w = fmaxf(v.w, 0.f);
            }
            *(float4*)&out[j][et * 4] = v;
        }
    }
}

__global__ __launch_bounds__(256, 2) void node_kernel(
    const float* __restrict__ Ep, int ncopies, size_t copy_elems,
    const float* __restrict__ W0, const float* __restrict__ B0,
    const float* __restrict__ W1, const float* __restrict__ B1,
    float* __restrict__ P, int n_nodes)
{
    __shared__ float bufA[104][64];
    __shared__ float bufB[104][64];
    const int tid = threadIdx.x;
    const int n0  = blockIdx.x * 64;

    for (int idx = tid; idx < 64 * 50; idx += 256) {
        const int e = idx / 50;
        const int k = idx - e * 50;
        const int n = n0 + e;
        float s = 0.f;
        if (n < n_nodes) {
            const float* p = &Ep[(size_t)n * 50 + k];
            for (int c = 0; c < ncopies; ++c) s += p[(size_t)c * copy_elems];
        }
        bufA[k][e] = s;
    }
    __syncthreads();
    mlp_layer_t<50, 100, true >(W0, B0, bufA, bufB, tid); __syncthreads();
    mlp_layer_t<100, 4, false>(W1, B1, bufB, bufA, tid); __syncthreads();
    for (int idx = tid; idx < 64 * 4; idx += 256) {
        const int e = idx & 63;
        const int j = idx >> 6;
        const int n = n0 + e;
        if (n < n_nodes) P[(size_t)n * 4 + j] = bufA[j][e];
    }
}

// ------------------------------- launcher -----------------------------------
extern "C" void kernel_launch(void* const* d_in, const int* in_sizes, int n_in,
                              void* d_out, int out_size, void* d_ws, size_t ws_size,
                              hipStream_t stream)
{
    const float* t   = (const float*)d_in[0];
    const float* x   = (const float*)d_in[1];
    const float* Ofx = (const float*)d_in[2];
    const int*   src = (const int*)d_in[3];
    const int*   tgt = (const int*)d_in[4];
    const float* W0  = (const float*)d_in[5];  const float* B0 = (const float*)d_in[6];
    const float* W1  = (const float*)d_in[7];  const float* B1 = (const float*)d_in[8];
    const float* W2  = (const float*)d_in[9];  const float* B2 = (const float*)d_in[10];
    const float* W3  = (const float*)d_in[11]; const float* B3 = (const float*)d_in[12];
    const float* W4  = (const float*)d_in[13]; const float* B4 = (const float*)d_in[14];
    const float* OW0 = (const float*)d_in[15]; const float* OB0 = (const float*)d_in[16];
    const float* OW1 = (const float*)d_in[17]; const float* OB1 = (const float*)d_in[18];

    const int n_nodes = in_sizes[1] / 4;
    const int n_edges = in_sizes[3];

    u16*   Wt = (u16*)d_ws;                                  // 256000 B
    float* Bp = (float*)((char*)d_ws + WT_BYTES);            // 5 x 160 floats
    float* Ep = (float*)((char*)d_ws + WS_HDR);              // ncopies x [N,50] fp32

    const size_t copy_elems = (size_t)n_nodes * 50;
    const size_t avail = (ws_size > WS_HDR) ? ws_size - WS_HDR : 0;
    int ncopies = 1;                                          // power of two, <= 2
    while (ncopies * 2 <= 2 &&
           (size_t)(ncopies * 2) * copy_elems * sizeof(float) <= avail)
        ncopies *= 2;
    const int copy_mask = ncopies - 1;

    prep_weights<<<dim3(32, 5), 256, 0, stream>>>(W0, W1, W2, W3, W4, Wt);
    prep_bias<<<4, 256, 0, stream>>>(B0, B1, B2, B3, B4, Bp);
    hipMemsetAsync(Ep, 0, (size_t)ncopies * copy_elems * sizeof(float), stream);

    edge_kernel<<<(n_edges + BLK_E - 1) / BLK_E, NTHR, 0, stream>>>(
        t, x, Ofx, src, tgt, Wt, Bp, Ep, n_edges, copy_mask, copy_elems);

    node_kernel<<<(n_nodes + 63) / 64, 256, 0, stream>>>(
        Ep, ncopies, copy_elems, OW0, OB0, OW1, OB1, (float*)d_out, n_nodes);
}

// Round 13
// 968.694 us; speedup vs baseline: 1.5861x; 1.1168x over previous
//
#include <hip/hip_runtime.h>
#include <hip/hip_bf16.h>

typedef unsigned short u16;
typedef __attribute__((ext_vector_type(8))) short short8;
typedef __attribute__((ext_vector_type(4))) float f32x4;

constexpr int SA     = 168;    // act row stride (bf16): 336 B -> 2-way banks (free)
constexpr int BLK_E  = 64;     // edges per block
constexpr int NTHR   = 192;    // 3 waves; N-split j: {0-3},{4-7},{8,9}; M shared (4 tiles)
constexpr int CHUNK  = 512;    // u16 elems per (ks,j) fragment chunk = 1 KB
constexpr int WSLOT  = 50 * CHUNK;              // 25600 elems per layer (5 ks x 10 j)
constexpr size_t WT_BYTES = 5ull * WSLOT * 2;   // 256000 B
constexpr size_t WS_HDR   = 262144;             // weights + padded bias

// slice schedule: s=0 -> (L0,ks0); s=1..15 -> L1..L3 (5 ks each); s=16..20 -> L4
constexpr int Ls (int s) { return s == 0 ? 0 : (s <= 15 ? 1 + (s - 1) / 5 : 4); }
constexpr int Kss(int s) { return s == 0 ? 0 : (s <= 15 ? (s - 1) % 5 : s - 16); }

__device__ __forceinline__ u16 f2bf(float f) {  // RNE (prep only)
    union { float f; unsigned u; } c; c.f = f;
    return (u16)((c.u + 0x7fffu + ((c.u >> 16) & 1u)) >> 16);
}
__device__ __forceinline__ unsigned pk_bf16(float a, float b) {  // v_cvt_pk_bf16_f32
    float2 f; f.x = a; f.y = b;
    __hip_bfloat162 h = __float22bfloat162_rn(f);
    return *(unsigned*)&h;
}

// act k'-storage (4/4/2 N-split): j<4: k'=col*4+j | j=4..7: 64+col*4+(j-4) | j=8,9: 128+col*2+(j-8)
__device__ __forceinline__ int kperm(int kp) {
    if (kp < 64)  return (kp & 3) * 16 + (kp >> 2);
    if (kp < 128) { const int m = kp - 64;  return (4 + (m & 3)) * 16 + (m >> 2); }
    if (kp < 160) { const int m = kp - 128; return (8 + (m & 1)) * 16 + (m >> 1); }
    return 1 << 30;
}

// ---- prep: weights -> fragment-ordered chunks (+ padded bias at y==5) ------
__global__ void prep_all(const float* __restrict__ W0, const float* __restrict__ W1,
                         const float* __restrict__ W2, const float* __restrict__ W3,
                         const float* __restrict__ W4,
                         const float* __restrict__ B0, const float* __restrict__ B1,
                         const float* __restrict__ B2, const float* __restrict__ B3,
                         const float* __restrict__ B4,
                         u16* __restrict__ Wt, float* __restrict__ Bp)
{
    const int l = blockIdx.y;
    if (l == 5) {   // bias: 5 x 160, zero-padded
        const int idx = blockIdx.x * blockDim.x + threadIdx.x;
        if (idx < 800) {
            const int ll = idx / 160, j = idx - ll * 160;
            const float* B; int DO;
            if      (ll == 0) { B = B0; DO = 150; }
            else if (ll == 1) { B = B1; DO = 150; }
            else if (ll == 2) { B = B2; DO = 150; }
            else if (ll == 3) { B = B3; DO = 150; }
            else              { B = B4; DO = 50;  }
            Bp[idx] = (j < DO) ? B[j] : 0.f;
        }
        return;
    }
    const float* W; int DI, DO; bool perm;
    if      (l == 0) { W = W0; DI = 13;  DO = 150; perm = false; }
    else if (l == 1) { W = W1; DI = 150; DO = 150; perm = true;  }
    else if (l == 2) { W = W2; DI = 150; DO = 150; perm = true;  }
    else if (l == 3) { W = W3; DI = 150; DO = 150; perm = true;  }
    else             { W = W4; DI = 150; DO = 50;  perm = true;  }
    u16* dst = Wt + (size_t)l * WSLOT;
    for (int idx = blockIdx.x * blockDim.x + threadIdx.x; idx < WSLOT;
         idx += gridDim.x * blockDim.x) {
        const int chunk = idx / CHUNK;            // = ks*10 + j
        const int within = idx - chunk * CHUNK;
        const int lane = within >> 3, e = within & 7;
        const int ks = chunk / 10, j = chunk - ks * 10;
        const int c = lane & 15, q = lane >> 4;
        const int n = j * 16 + c;
        const int kphys = ks * 32 + q * 8 + e;
        const int klog = perm ? kperm(kphys) : kphys;
        const float v = (n < DO && klog < DI) ? W[klog * DO + n] : 0.f;
        dst[idx] = f2bf(v);
    }
}

// ---- B-load for slice s into a window slot (plain global->VGPR, coalesced) -
__device__ __forceinline__ void loadB(const u16* __restrict__ Wt, int s,
                                      int wv, int lane, short8 (&slot)[4])
{
    const int l = Ls(s), ks = Kss(s);
    const int jb = (l < 4) ? wv * 4 : 0;
    const int nt = (l < 4 && wv == 2) ? 2 : 4;
    const u16* base = Wt + (size_t)l * WSLOT + (size_t)(ks * 10 + jb) * CHUNK + lane * 8;
#pragma unroll
    for (int jj = 0; jj < 4; ++jj)
        if (jj < nt) slot[jj] = *(const short8*)&base[jj * CHUNK];
}

// ---- epilogue: bias+relu, packed bf16, k'-permuted in-place store ----------
__device__ __forceinline__ void epilogue(u16* act, const float* __restrict__ Bp,
                                         int l, int wv, int col, int quad,
                                         f32x4 (&acc)[4][4])
{
    const int jb = wv * 4;
    float bb[4];
#pragma unroll
    for (int jj = 0; jj < 4; ++jj) bb[jj] = Bp[l * 160 + (jb + jj) * 16 + col];
#pragma unroll
    for (int mt = 0; mt < 4; ++mt)
#pragma unroll
        for (int r = 0; r < 4; ++r) {
            u16* row = &act[(mt * 16 + quad * 4 + r) * SA];
            if (wv < 2) {
                uint2 pk;
                pk.x = pk_bf16(fmaxf(acc[mt][0][r] + bb[0], 0.f),
                               fmaxf(acc[mt][1][r] + bb[1], 0.f));
                pk.y = pk_bf16(fmaxf(acc[mt][2][r] + bb[2], 0.f),
                               fmaxf(acc[mt][3][r] + bb[3], 0.f));
                *(uint2*)&row[wv * 64 + col * 4] = pk;             // b64
            } else {
                *(unsigned*)&row[128 + col * 2] =                   // b32
                    pk_bf16(fmaxf(acc[mt][0][r] + bb[0], 0.f),
                            fmaxf(acc[mt][1][r] + bb[1], 0.f));
            }
        }
}

// ------------------------------- Edge kernel --------------------------------
// 3 waves, N-split (4/4/2 N-tiles) over all 64 edges. B: global->VGPR rolling
// 3-slice window (no LDS staging, no per-slice barriers). Sync: 1 post-gather
// + 2 per layer boundary (epilogue write vs A-read ordering) = 9 barriers.
// LDS 21.8 KB, VGPR<=170 -> 4 blocks x 3 waves = 12 waves/CU.
__global__ __launch_bounds__(NTHR, 3) void edge_kernel(
    const float* __restrict__ t, const float* __restrict__ x, const float* __restrict__ Ofx,
    const int* __restrict__ src, const int* __restrict__ tgt,
    const u16* __restrict__ Wt, const float* __restrict__ Bp,
    float* __restrict__ Ep, int n_edges, int copy_mask, size_t copy_elems)
{
    __shared__ __align__(16) u16 act[BLK_E * SA];      // 21504 B
    __shared__ int tgt_s[BLK_E];                       // 256 B

    const int tid  = threadIdx.x;
    const int lane = tid & 63;
    const int wv   = tid >> 6;
    const int col  = lane & 15;
    const int quad = lane >> 4;

    const int xcd = (int)(__builtin_amdgcn_s_getreg(6164) & 7u) & copy_mask;
    float* __restrict__ Epc = Ep + (size_t)xcd * copy_elems;

    short8 Bwin[3][4];
    loadB(Wt, 0, wv, lane, Bwin[0]);    // prologue: 3-deep lookahead
    loadB(Wt, 1, wv, lane, Bwin[1]);
    loadB(Wt, 2, wv, lane, Bwin[2]);

    // ---- gather R' (wave 0; visible to all after first barrier) ----
    if (tid < BLK_E) {
        const int e = tid;
        const long long ge = (long long)blockIdx.x * BLK_E + e;
        const bool valid = ge < n_edges;
        const int s = valid ? src[ge] : 0;
        const int g = valid ? tgt[ge] : 0;
        const float4 xs = valid ? *(const float4*)&x[(size_t)s * 4] : float4{0, 0, 0, 0};
        const float2 os = valid ? *(const float2*)&Ofx[(size_t)s * 2] : float2{0, 0};
        const float4 xg = valid ? *(const float4*)&x[(size_t)g * 4] : float4{0, 0, 0, 0};
        const float2 og = valid ? *(const float2*)&Ofx[(size_t)g * 2] : float2{0, 0};
        const float tv = valid ? t[0] : 0.f;
        uint4 w0, w1;
        w0.x = pk_bf16(xs.x, xs.y); w0.y = pk_bf16(xs.z, xs.w);
        w0.z = pk_bf16(os.x, os.y); w0.w = pk_bf16(xg.x, xg.y);
        w1.x = pk_bf16(xg.z, xg.w); w1.y = pk_bf16(og.x, og.y);
        w1.z = pk_bf16(tv, 0.f);    w1.w = 0u;
        u16* row = &act[e * SA];
        *(uint4*)&row[0]  = w0;
        *(uint4*)&row[8]  = w1;
        *(uint4*)&row[16] = uint4{0, 0, 0, 0};
        *(uint4*)&row[24] = uint4{0, 0, 0, 0};
        tgt_s[e] = valid ? g : -1;
    }
    __syncthreads();

    const int ntw = (wv == 2) ? 2 : 4;     // N-tiles this wave (hidden layers)
    f32x4 acc[4][4];
    short8 Af[4];

    // ---- s=0: L0 (K=32) ----
#pragma unroll
    for (int mt = 0; mt < 4; ++mt)
#pragma unroll
        for (int jj = 0; jj < 4; ++jj) acc[mt][jj] = f32x4{0.f, 0.f, 0.f, 0.f};
#pragma unroll
    for (int mt = 0; mt < 4; ++mt)
        Af[mt] = *(const short8*)&act[(mt * 16 + col) * SA + quad * 8];
#pragma unroll
    for (int jj = 0; jj < 4; ++jj)
        if (jj < ntw)
#pragma unroll
            for (int mt = 0; mt < 4; ++mt)
                acc[mt][jj] = __builtin_amdgcn_mfma_f32_16x16x32_bf16(
                    Af[mt], Bwin[0][jj], acc[mt][jj], 0, 0, 0);
    loadB(Wt, 3, wv, lane, Bwin[0]);       // refill slot 0 (s=3)
    __syncthreads();                        // A-reads done
    epilogue(act, Bp, 0, wv, col, quad, acc);
    __syncthreads();                        // epilogue visible

    // ---- s=1..15: L1..L3 ----
#pragma unroll
    for (int s = 1; s <= 15; ++s) {
        const int l = 1 + (s - 1) / 5;
        const int ks = (s - 1) % 5;
        const int slot = s % 3;
        if (ks == 0) {
#pragma unroll
            for (int mt = 0; mt < 4; ++mt)
#pragma unroll
                for (int jj = 0; jj < 4; ++jj) acc[mt][jj] = f32x4{0.f, 0.f, 0.f, 0.f};
        }
#pragma unroll
        for (int mt = 0; mt < 4; ++mt)
            Af[mt] = *(const short8*)&act[(mt * 16 + col) * SA + ks * 32 + quad * 8];
#pragma unroll
        for (int jj = 0; jj < 4; ++jj)
            if (jj < ntw)
#pragma unroll
                for (int mt = 0; mt < 4; ++mt)
                    acc[mt][jj] = __builtin_amdgcn_mfma_f32_16x16x32_bf16(
                        Af[mt], Bwin[slot][jj], acc[mt][jj], 0, 0, 0);
        if (s + 3 <= 20) loadB(Wt, s + 3, wv, lane, Bwin[slot]);
        if (ks == 4) {
            __syncthreads();                // all A-reads of layer l done
            epilogue(act, Bp, l, wv, col, quad, acc);
            __syncthreads();                // epilogue visible
        }
    }

    // ---- s=16..20: L4 (M-split: wave0 mt{0,1}, wave1 {2}, wave2 {3}) ----
    const int mb  = (wv == 0) ? 0 : wv + 1;
    const int nmt = (wv == 0) ? 2 : 1;
    f32x4 acc4[2][4];
#pragma unroll
    for (int k = 0; k < 2; ++k)
#pragma unroll
        for (int jj = 0; jj < 4; ++jj) acc4[k][jj] = f32x4{0.f, 0.f, 0.f, 0.f};
#pragma unroll
    for (int s = 16; s <= 20; ++s) {
        const int ks = s - 16;
        const int slot = s % 3;
        short8 A4[2];
#pragma unroll
        for (int k = 0; k < 2; ++k)
            if (k < nmt)
                A4[k] = *(const short8*)&act[((mb + k) * 16 + col) * SA + ks * 32 + quad * 8];
#pragma unroll
        for (int jj = 0; jj < 4; ++jj)
#pragma unroll
            for (int k = 0; k < 2; ++k)
                if (k < nmt)
                    acc4[k][jj] = __builtin_amdgcn_mfma_f32_16x16x32_bf16(
                        A4[k], Bwin[slot][jj], acc4[k][jj], 0, 0, 0);
        if (s + 3 <= 20) loadB(Wt, s + 3, wv, lane, Bwin[slot]);  // FIX: refill 19,20
    }

    // ---- scatter-add E into XCD-local Ep copy ----
#pragma unroll
    for (int jj = 0; jj < 4; ++jj) {
        const int n = jj * 16 + col;
        if (n < 50) {
            const float bb = Bp[4 * 160 + n];
#pragma unroll
            for (int k = 0; k < 2; ++k)
                if (k < nmt)
#pragma unroll
                    for (int r = 0; r < 4; ++r) {
                        const int g = tgt_s[(mb + k) * 16 + quad * 4 + r];
                        if (g >= 0) atomicAdd(&Epc[(size_t)g * 50 + n], acc4[k][jj][r] + bb);
                    }
        }
    }
}

// ---------------- Node kernel: reduce copies + fO MLP (fp32 VALU) -----------
template<int DI, int DO, bool RELU>
__device__ __forceinline__ void mlp_layer_t(
    const float* __restrict__ W, const float* __restrict__ B,
    float (*in)[64], float (*out)[64], int tid)
{
    const int et = tid & 15;
    const int jt = tid >> 4;
    constexpr int NG = (DO + 15) / 16;

    float acc0[NG], acc1[NG], acc2[NG], acc3[NG];
#pragma unroll
    for (int g = 0; g < NG; ++g) {
        const int j = jt + 16 * g;
        const float bb = (j < DO) ? B[j] : 0.f;
        acc0[g] = bb; acc1[g] = bb; acc2[g] = bb; acc3[g] = bb;
    }
    for (int k = 0; k < DI; ++k) {
        const float4 a = *(const float4*)&in[k][et * 4];
#pragma unroll
        for (int g = 0; g < NG; ++g) {
            const int j = jt + 16 * g;
            const float wv = (j < DO) ? W[k * DO + j] : 0.f;
            acc0[g] = fmaf(a.x, wv, acc0[g]);
            acc1[g] = fmaf(a.y, wv, acc1[g]);
            acc2[g] = fmaf(a.z, wv, acc2[g]);
            acc3[g] = fmaf(a.w, wv, acc3[g]);
        }
    }
#pragma unroll
    for (int g = 0; g < NG; ++g) {
        const int j = jt + 16 * g;
        if (j < DO) {
            float4 v; v.x = acc0[g]; v.y = acc1[g]; v.z = acc2[g]; v.w = acc3[g];
            if (RELU) {
                v.x = fmaxf(v.x, 0.f); v.y = fmaxf(v.y, 0.f);
                v.z = fmaxf(v.z, 0.f); v.w = fmaxf(v.w, 0.f);
            }
            *(float4*)&out[j][et * 4] = v;
        }
    }
}

__global__ __launch_bounds__(256, 2) void node_kernel(
    const float* __restrict__ Ep, int ncopies, size_t copy_elems,
    const float* __restrict__ W0, const float* __restrict__ B0,
    const float* __restrict__ W1, const float* __restrict__ B1,
    float* __restrict__ P, int n_nodes)
{
    __shared__ float bufA[104][64];
    __shared__ float bufB[104][64];
    const int tid = threadIdx.x;
    const int n0  = blockIdx.x * 64;

    for (int idx = tid; idx < 64 * 50; idx += 256) {
        const int e = idx / 50;
        const int k = idx - e * 50;
        const int n = n0 + e;
        float s = 0.f;
        if (n < n_nodes) {
            const float* p = &Ep[(size_t)n * 50 + k];
            for (int c = 0; c < ncopies; ++c) s += p[(size_t)c * copy_elems];
        }
        bufA[k][e] = s;
    }
    __syncthreads();
    mlp_layer_t<50, 100, true >(W0, B0, bufA, bufB, tid); __syncthreads();
    mlp_layer_t<100, 4, false>(W1, B1, bufB, bufA, tid); __syncthreads();
    for (int idx = tid; idx < 64 * 4; idx += 256) {
        const int e = idx & 63;
        const int j = idx >> 6;
        const int n = n0 + e;
        if (n < n_nodes) P[(size_t)n * 4 + j] = bufA[j][e];
    }
}

// ------------------------------- launcher -----------------------------------
extern "C" void kernel_launch(void* const* d_in, const int* in_sizes, int n_in,
                              void* d_out, int out_size, void* d_ws, size_t ws_size,
                              hipStream_t stream)
{
    const float* t   = (const float*)d_in[0];
    const float* x   = (const float*)d_in[1];
    const float* Ofx = (const float*)d_in[2];
    const int*   src = (const int*)d_in[3];
    const int*   tgt = (const int*)d_in[4];
    const float* W0  = (const float*)d_in[5];  const float* B0 = (const float*)d_in[6];
    const float* W1  = (const float*)d_in[7];  const float* B1 = (const float*)d_in[8];
    const float* W2  = (const float*)d_in[9];  const float* B2 = (const float*)d_in[10];
    const float* W3  = (const float*)d_in[11]; const float* B3 = (const float*)d_in[12];
    const float* W4  = (const float*)d_in[13]; const float* B4 = (const float*)d_in[14];
    const float* OW0 = (const float*)d_in[15]; const float* OB0 = (const float*)d_in[16];
    const float* OW1 = (const float*)d_in[17]; const float* OB1 = (const float*)d_in[18];

    const int n_nodes = in_sizes[1] / 4;
    const int n_edges = in_sizes[3];

    u16*   Wt = (u16*)d_ws;                                  // 256000 B
    float* Bp = (float*)((char*)d_ws + WT_BYTES);            // 5 x 160 floats
    float* Ep = (float*)((char*)d_ws + WS_HDR);              // ncopies x [N,50] fp32

    const size_t copy_elems = (size_t)n_nodes * 50;
    const size_t avail = (ws_size > WS_HDR) ? ws_size - WS_HDR : 0;
    int ncopies = 1;                                          // power of two, <= 2
    while (ncopies * 2 <= 2 &&
           (size_t)(ncopies * 2) * copy_elems * sizeof(float) <= avail)
        ncopies *= 2;
    const int copy_mask = ncopies - 1;

    prep_all<<<dim3(32, 6), 256, 0, stream>>>(W0, W1, W2, W3, W4,
                                              B0, B1, B2, B3, B4, Wt, Bp);
    hipMemsetAsync(Ep, 0, (size_t)ncopies * copy_elems * sizeof(float), stream);

    edge_kernel<<<(n_edges + BLK_E - 1) / BLK_E, NTHR, 0, stream>>>(
        t, x, Ofx, src, tgt, Wt, Bp, Ep, n_edges, copy_mask, copy_elems);

    node_kernel<<<(n_nodes + 63) / 64, 256, 0, stream>>>(
        Ep, ncopies, copy_elems, OW0, OB0, OW1, OB1, (float*)d_out, n_nodes);
}